// Round 4
// baseline (458.045 us; speedup 1.0000x reference)
//
#include <hip/hip_runtime.h>
#include <hip/hip_bf16.h>

// Problem constants
#define PN 16384
#define PZ 100
#define PE 400
#define PM0 4000
#define PM1 2000
#define KP 128            // packed K: [0,100) = f16 data, [100,128) = zero
#define MB1 4032          // B2T row base of segment 1 (seg0 pads 4000->4032)
#define MROWS 6080        // 4032 + 2048 total B2T rows

typedef __attribute__((ext_vector_type(8))) _Float16 half8v;
typedef __attribute__((ext_vector_type(4))) float floatx4;
typedef __attribute__((ext_vector_type(4))) unsigned int uint4v;

__device__ __forceinline__ void gload16(const void* g, void* l) {
    __builtin_amdgcn_global_load_lds(
        (const __attribute__((address_space(1))) void*)g,
        (__attribute__((address_space(3))) void*)l, 16, 0, 0);
}

// ---------------------------------------------------------------------------
// zero-fill (16B granular)
// ---------------------------------------------------------------------------
__global__ __launch_bounds__(256) void fill_kernel(uint4v* __restrict__ p, int n16)
{
    int i = blockIdx.x * 256 + threadIdx.x;
    if (i < n16) p[i] = (uint4v){0u, 0u, 0u, 0u};
}

// ---------------------------------------------------------------------------
// topic: b2t[m][z] = f16( sum_e beta[z][e] * alpha[m][e] )  -- transposed f16
// ---------------------------------------------------------------------------
__global__ __launch_bounds__(256) void topic_kernel(
    const float* __restrict__ alpha, const float* __restrict__ beta,
    _Float16* __restrict__ b2t, int M)
{
    __shared__ float sA[64][201];
    const int tid = threadIdx.x;
    const int ml = tid & 63;
    const int zt = tid >> 6;
    const int m0 = blockIdx.x * 64;
    const int z0 = blockIdx.y * 20 + zt * 5;

    float acc[5] = {0.f, 0.f, 0.f, 0.f, 0.f};

    for (int ec = 0; ec < 2; ++ec) {
        #pragma unroll
        for (int l = 0; l < 50; ++l) {
            int idx = tid + l * 256;
            int mr = idx / 200;
            int e  = idx - mr * 200;
            int m  = m0 + mr;
            sA[mr][e] = (m < M) ? alpha[(size_t)m * PE + ec * 200 + e] : 0.f;
        }
        __syncthreads();
        const float* bz = beta + (size_t)z0 * PE + ec * 200;
        #pragma unroll 4
        for (int e = 0; e < 200; ++e) {
            float a = sA[ml][e];
            #pragma unroll
            for (int zi = 0; zi < 5; ++zi)
                acc[zi] = fmaf(bz[zi * PE + e], a, acc[zi]);
        }
        __syncthreads();
    }
    int m = m0 + ml;
    if (m < M) {
        #pragma unroll
        for (int zi = 0; zi < 5; ++zi)
            b2t[(size_t)m * KP + (z0 + zi)] = (_Float16)acc[zi];
    }
}

// ---------------------------------------------------------------------------
// Fused GEMM + online LSE + writeout.
// Block: 256 threads (4 waves), owns 64 output rows x one full segment.
// Wave w handles col-slice [w*16, w*16+16) of each 64-col tile.
// Sweep 1: MFMA per tile + bias + per-lane running max/sumexp (no storage).
// Reduce: 16-lane shfl + cross-wave LDS -> per-row LSE.
// Sweep 2: recompute MFMA per tile, write logit + bias - lse to out (f32).
// ---------------------------------------------------------------------------
__global__ __launch_bounds__(256) void fused_kernel(
    const float* __restrict__ theta,
    const _Float16* __restrict__ B2T,
    const float* __restrict__ bias0, const float* __restrict__ bias1,
    const int* __restrict__ dom,
    float* __restrict__ out0, float* __restrict__ out1)
{
    __shared__ __align__(1024) _Float16 sA[64 * 128];  // 16 KB, rows of 256 B
    __shared__ __align__(1024) _Float16 sB[64 * 128];  // 16 KB
    __shared__ float swx[4][64];
    __shared__ float sws[4][64];
    __shared__ float slse[64];
    __shared__ int   sdom[64];

    const int tid = threadIdx.x;
    const int w   = tid >> 6;
    const int ll  = tid & 63;
    const int g   = ll >> 4;     // 0..3  (k-slot group / row sub-block)
    const int c   = ll & 15;     // 0..15 (fragment row index)

    const int seg = blockIdx.x & 1;
    const int n0  = (blockIdx.x >> 1) * 64;
    const int M   = seg ? PM1 : PM0;
    const int NT  = seg ? 32 : 63;                    // 64-col tiles
    const _Float16* Bseg = B2T + (size_t)(seg ? MB1 : 0) * KP;
    const float* bias = seg ? bias1 : bias0;
    float* out = seg ? out1 : out0;

    // ---- stage A panel: theta f32 -> f16, swizzled rows of 16 slots ----
    {
        int row = tid >> 2;              // 0..63
        int sg  = (tid & 3) * 4;         // first of 4 slots
        const float* tr = theta + (size_t)(n0 + row) * PZ;
        #pragma unroll
        for (int s = sg; s < sg + 4; ++s) {
            int k = s * 8;
            float4 lo = (k < PZ) ? *(const float4*)&tr[k] : make_float4(0.f,0.f,0.f,0.f);
            float4 hi = (k + 4 < PZ) ? *(const float4*)&tr[k+4] : make_float4(0.f,0.f,0.f,0.f);
            half8v h;
            h[0] = (_Float16)lo.x; h[1] = (_Float16)lo.y;
            h[2] = (_Float16)lo.z; h[3] = (_Float16)lo.w;
            h[4] = (_Float16)hi.x; h[5] = (_Float16)hi.y;
            h[6] = (_Float16)hi.z; h[7] = (_Float16)hi.w;
            *(half8v*)((char*)sA + row * 256 + ((s ^ (row & 7)) * 16)) = h;
        }
        if (tid < 64) sdom[tid] = dom[n0 + tid];
    }
    __syncthreads();

    // ---- A fragments to registers (held across both sweeps) ----
    half8v aF[4][4];
    #pragma unroll
    for (int mi = 0; mi < 4; ++mi) {
        int row = mi * 16 + c;
        #pragma unroll
        for (int kb = 0; kb < 4; ++kb) {
            int slot = (kb * 4 + g) ^ (row & 7);
            aF[mi][kb] = *(const half8v*)((const char*)sA + row * 256 + slot * 16);
        }
    }

    // per-lane online stats: rows mi*16 + 4g + i, col-slice of this lane
    float mx[4][4], sm[4][4];
    #pragma unroll
    for (int mi = 0; mi < 4; ++mi)
        #pragma unroll
        for (int i = 0; i < 4; ++i) { mx[mi][i] = -3.0e38f; sm[mi][i] = 0.f; }

    const int srow  = ll >> 4;   // staging: row within 4-row instr
    const int sslot = ll & 15;   // staging: dest slot (linear)
    __syncthreads();             // sA reads done before any reuse patterns

    // =================== sweep 1: stats ===================
    for (int t = 0; t < NT; ++t) {
        const int m0t = t * 64;
        #pragma unroll
        for (int it = 0; it < 4; ++it) {
            int row  = w * 16 + it * 4 + srow;
            int slot = sslot ^ (row & 7);
            gload16(Bseg + ((size_t)(m0t + row)) * KP + slot * 8,
                    (char*)sB + (size_t)(w * 16 + it * 4) * 256);
        }
        __syncthreads();   // drains vmcnt, sB ready

        half8v bF[4];
        const int brow = w * 16 + c;
        #pragma unroll
        for (int kb = 0; kb < 4; ++kb) {
            int slot = (kb * 4 + g) ^ (brow & 7);
            bF[kb] = *(const half8v*)((const char*)sB + brow * 256 + slot * 16);
        }

        const int m  = m0t + w * 16 + c;
        const bool mv = (m < M);
        const int mc = mv ? m : (M - 1);
        float bv0 = bias[0 * (size_t)M + mc];
        float bv1 = bias[1 * (size_t)M + mc];
        float bv2 = bias[2 * (size_t)M + mc];
        float bv3 = bias[3 * (size_t)M + mc];

        floatx4 acc[4];
        #pragma unroll
        for (int mi = 0; mi < 4; ++mi) acc[mi] = (floatx4){0.f, 0.f, 0.f, 0.f};
        #pragma unroll
        for (int mi = 0; mi < 4; ++mi)
            #pragma unroll
            for (int kb = 0; kb < 4; ++kb)
                acc[mi] = __builtin_amdgcn_mfma_f32_16x16x32_f16(
                    aF[mi][kb], bF[kb], acc[mi], 0, 0, 0);

        #pragma unroll
        for (int mi = 0; mi < 4; ++mi) {
            #pragma unroll
            for (int i = 0; i < 4; ++i) {
                int row = mi * 16 + 4 * g + i;
                int d = sdom[row];
                float bv = (d < 2) ? (d == 0 ? bv0 : bv1) : (d == 2 ? bv2 : bv3);
                float v = mv ? (acc[mi][i] + bv) : -3.0e38f;
                float nm = fmaxf(mx[mi][i], v);
                sm[mi][i] = sm[mi][i] * __expf(mx[mi][i] - nm) + __expf(v - nm);
                mx[mi][i] = nm;
            }
        }
        __syncthreads();   // all reads of sB done before restage
    }

    // ---- cross-lane reduce over the 16 c-lanes ----
    #pragma unroll
    for (int mi = 0; mi < 4; ++mi) {
        #pragma unroll
        for (int i = 0; i < 4; ++i) {
            float m_ = mx[mi][i], s_ = sm[mi][i];
            #pragma unroll
            for (int msk = 1; msk < 16; msk <<= 1) {
                float mo = __shfl_xor(m_, msk);
                float so = __shfl_xor(s_, msk);
                float nm = fmaxf(m_, mo);
                s_ = s_ * __expf(m_ - nm) + so * __expf(mo - nm);
                m_ = nm;
            }
            if (c == 0) {
                int row = mi * 16 + 4 * g + i;
                swx[w][row] = m_;
                sws[w][row] = s_;
            }
        }
    }
    __syncthreads();

    // ---- cross-wave reduce -> per-row LSE ----
    if (tid < 64) {
        float m_ = swx[0][tid], s_ = sws[0][tid];
        #pragma unroll
        for (int wv = 1; wv < 4; ++wv) {
            float mo = swx[wv][tid];
            float so = sws[wv][tid];
            float nm = fmaxf(m_, mo);
            s_ = s_ * __expf(m_ - nm) + so * __expf(mo - nm);
            m_ = nm;
        }
        slse[tid] = m_ + __logf(s_);
    }
    __syncthreads();

    // =================== sweep 2: recompute + write ===================
    for (int t = 0; t < NT; ++t) {
        const int m0t = t * 64;
        #pragma unroll
        for (int it = 0; it < 4; ++it) {
            int row  = w * 16 + it * 4 + srow;
            int slot = sslot ^ (row & 7);
            gload16(Bseg + ((size_t)(m0t + row)) * KP + slot * 8,
                    (char*)sB + (size_t)(w * 16 + it * 4) * 256);
        }
        __syncthreads();

        half8v bF[4];
        const int brow = w * 16 + c;
        #pragma unroll
        for (int kb = 0; kb < 4; ++kb) {
            int slot = (kb * 4 + g) ^ (brow & 7);
            bF[kb] = *(const half8v*)((const char*)sB + brow * 256 + slot * 16);
        }

        const int m  = m0t + w * 16 + c;
        const bool mv = (m < M);
        const int mc = mv ? m : (M - 1);
        float bv0 = bias[0 * (size_t)M + mc];
        float bv1 = bias[1 * (size_t)M + mc];
        float bv2 = bias[2 * (size_t)M + mc];
        float bv3 = bias[3 * (size_t)M + mc];

        floatx4 acc[4];
        #pragma unroll
        for (int mi = 0; mi < 4; ++mi) acc[mi] = (floatx4){0.f, 0.f, 0.f, 0.f};
        #pragma unroll
        for (int mi = 0; mi < 4; ++mi)
            #pragma unroll
            for (int kb = 0; kb < 4; ++kb)
                acc[mi] = __builtin_amdgcn_mfma_f32_16x16x32_f16(
                    aF[mi][kb], bF[kb], acc[mi], 0, 0, 0);

        if (mv) {
            #pragma unroll
            for (int mi = 0; mi < 4; ++mi) {
                #pragma unroll
                for (int i = 0; i < 4; ++i) {
                    int row = mi * 16 + 4 * g + i;
                    int d = sdom[row];
                    float bv = (d < 2) ? (d == 0 ? bv0 : bv1) : (d == 2 ? bv2 : bv3);
                    out[(size_t)(n0 + row) * M + m] = acc[mi][i] + bv - slse[row];
                }
            }
        }
        __syncthreads();
    }
}

// ---------------------------------------------------------------------------
extern "C" void kernel_launch(void* const* d_in, const int* in_sizes, int n_in,
                              void* d_out, int out_size, void* d_ws, size_t ws_size,
                              hipStream_t stream) {
    const float* theta  = (const float*)d_in[0];
    const float* alpha0 = (const float*)d_in[1];
    const float* alpha1 = (const float*)d_in[2];
    const float* beta   = (const float*)d_in[3];
    const float* bias0  = (const float*)d_in[4];
    const float* bias1  = (const float*)d_in[5];
    const int*   dom    = (const int*)d_in[6];

    float* out0 = (float*)d_out;
    float* out1 = out0 + (size_t)PN * PM0;

    _Float16* B2T = (_Float16*)d_ws;   // [MROWS][KP] f16, 1.56 MB

    // 1. zero B2T (pad rows / pad k)
    {
        int n16 = MROWS * KP * 2 / 16;
        fill_kernel<<<(n16 + 255) / 256, 256, 0, stream>>>((uint4v*)B2T, n16);
    }

    // 2. topic -> B2T f16 (transposed): seg0 rows [0,4000), seg1 rows [4032, 6032)
    topic_kernel<<<dim3(63, 5), 256, 0, stream>>>(alpha0, beta, B2T, PM0);
    topic_kernel<<<dim3(32, 5), 256, 0, stream>>>(alpha1, beta, B2T + (size_t)MB1 * KP, PM1);

    // 3. fused GEMM + LSE + writeout (seg interleaved in blockIdx parity)
    fused_kernel<<<512, 256, 0, stream>>>(theta, B2T, bias0, bias1, dom, out0, out1);
}

// Round 6
// 367.744 us; speedup vs baseline: 1.2456x; 1.2456x over previous
//
#include <hip/hip_runtime.h>
#include <hip/hip_bf16.h>

// Problem constants
#define PN 16384
#define PZ 100
#define PE 400
#define PM0 4000
#define PM1 2000
#define KP 128            // packed K: [0,100) = f16 data, [100,128) = zero
#define SEG1 4096         // B2T row / logit col base of segment 1
#define MPAD 6144         // 4096 (seg0) + 2048 (seg1)

typedef __attribute__((ext_vector_type(8))) _Float16 half8v;
typedef __attribute__((ext_vector_type(4))) float floatx4;
typedef __attribute__((ext_vector_type(4))) unsigned int uint4v;

__device__ __forceinline__ void gload16(const void* g, void* l) {
    __builtin_amdgcn_global_load_lds(
        (const __attribute__((address_space(1))) void*)g,
        (__attribute__((address_space(3))) void*)l, 16, 0, 0);
}

// ---------------------------------------------------------------------------
// zero-fill B2T (pad rows + pad k stay deterministically zero)
// ---------------------------------------------------------------------------
__global__ __launch_bounds__(256) void fill_kernel(uint4v* __restrict__ p, int n16)
{
    int i = blockIdx.x * 256 + threadIdx.x;
    if (i < n16) p[i] = (uint4v){0u, 0u, 0u, 0u};
}

// ---------------------------------------------------------------------------
// topic (both segments, one dispatch):
// b2t[rowbase+m][z] = f16( sum_e beta[z][e] * alpha[m][e] )
// grid dim3(96, 5): x<64 -> seg0 m-tile, x>=64 -> seg1 m-tile; y = z-group
// ---------------------------------------------------------------------------
__global__ __launch_bounds__(256) void topic_kernel(
    const float* __restrict__ alpha0, const float* __restrict__ alpha1,
    const float* __restrict__ beta, _Float16* __restrict__ b2t)
{
    const int seg = (blockIdx.x >= 64);
    const int tile = seg ? (blockIdx.x - 64) : blockIdx.x;
    const float* alpha = seg ? alpha1 : alpha0;
    const int M = seg ? PM1 : PM0;
    const int rowbase = seg ? SEG1 : 0;

    __shared__ float sA[64][201];
    const int tid = threadIdx.x;
    const int ml = tid & 63;
    const int zt = tid >> 6;
    const int m0 = tile * 64;
    const int z0 = blockIdx.y * 20 + zt * 5;

    float acc[5] = {0.f, 0.f, 0.f, 0.f, 0.f};

    for (int ec = 0; ec < 2; ++ec) {
        #pragma unroll
        for (int l = 0; l < 50; ++l) {
            int idx = tid + l * 256;
            int mr = idx / 200;
            int e  = idx - mr * 200;
            int m  = m0 + mr;
            sA[mr][e] = (m < M) ? alpha[(size_t)m * PE + ec * 200 + e] : 0.f;
        }
        __syncthreads();
        const float* bz = beta + (size_t)z0 * PE + ec * 200;
        #pragma unroll 4
        for (int e = 0; e < 200; ++e) {
            float a = sA[ml][e];
            #pragma unroll
            for (int zi = 0; zi < 5; ++zi)
                acc[zi] = fmaf(bz[zi * PE + e], a, acc[zi]);
        }
        __syncthreads();
    }
    int m = m0 + ml;
    if (m < M) {
        #pragma unroll
        for (int zi = 0; zi < 5; ++zi)
            b2t[(size_t)(rowbase + m) * KP + (z0 + zi)] = (_Float16)acc[zi];
    }
}

// ---------------------------------------------------------------------------
// GEMM + bias: logit[n][mc] = f16( sum_k theta[n][k]*topic[k][mc] + bias[dom[n]][mc] )
// 128x128 tile, 4 waves (2x2), 16x16x32_f16, full K=128 staged once.
// A converted f32->f16 in-kernel (swizzled ds_write); B via swizzled global_load_lds.
// ---------------------------------------------------------------------------
__global__ __launch_bounds__(256) void gemm_kernel(
    const float* __restrict__ theta,
    const _Float16* __restrict__ B2T,    // [MPAD][KP]
    const float* __restrict__ bias0, const float* __restrict__ bias1,
    const int* __restrict__ dom,
    unsigned short* __restrict__ logit)  // [PN][MPAD] f16 bits
{
    __shared__ __align__(1024) _Float16 sA[128 * 128];  // 32 KB, rows of 256 B
    __shared__ __align__(1024) _Float16 sB[128 * 128];  // 32 KB
    __shared__ int sdom[128];

    const int tid = threadIdx.x;
    const int w   = tid >> 6;
    const int ll  = tid & 63;
    const int g   = ll >> 4;     // 0..3
    const int c   = ll & 15;     // 0..15
    const int wrow = (w & 1) * 64;
    const int wcol = (w >> 1) * 64;

    const int n0   = blockIdx.y * 128;
    const int mcol = blockIdx.x * 128;          // global padded col base
    const int seg  = (mcol >= SEG1);
    const int M    = seg ? PM1 : PM0;
    const int mloc = mcol - (seg ? SEG1 : 0);   // segment-local col base
    const float* bias = seg ? bias1 : bias0;

    // ---- A stage: theta f32 -> f16, swizzled 16B slots ----
    #pragma unroll
    for (int p = 0; p < 8; ++p) {
        int idx2 = tid + p * 256;        // over 128 rows x 16 slots
        int row  = idx2 >> 4;
        int slot = idx2 & 15;
        const float* tr = theta + (size_t)(n0 + row) * PZ + slot * 8;
        half8v h;
        if (slot < 12) {
            float4 lo = *(const float4*)tr;
            float4 hi = *(const float4*)(tr + 4);
            h[0] = (_Float16)lo.x; h[1] = (_Float16)lo.y;
            h[2] = (_Float16)lo.z; h[3] = (_Float16)lo.w;
            h[4] = (_Float16)hi.x; h[5] = (_Float16)hi.y;
            h[6] = (_Float16)hi.z; h[7] = (_Float16)hi.w;
        } else if (slot == 12) {
            float4 lo = *(const float4*)tr;   // k = 96..99 (end of row)
            h[0] = (_Float16)lo.x; h[1] = (_Float16)lo.y;
            h[2] = (_Float16)lo.z; h[3] = (_Float16)lo.w;
            h[4] = (_Float16)0.f; h[5] = (_Float16)0.f;
            h[6] = (_Float16)0.f; h[7] = (_Float16)0.f;
        } else {
            h = (half8v)(_Float16)0.f;
        }
        *(half8v*)((char*)sA + row * 256 + ((slot ^ (row & 7)) * 16)) = h;
    }
    if (tid < 128) sdom[tid] = dom[n0 + tid];

    // ---- B stage: swizzled global_load_lds, 8 instrs x (4 rows/wave) ----
    {
        const int srow  = ll >> 4;
        const int sslot = ll & 15;
        #pragma unroll
        for (int it = 0; it < 8; ++it) {
            int row  = w * 32 + it * 4 + srow;
            int slot = sslot ^ (row & 7);
            gload16(B2T + (size_t)(mcol + row) * KP + slot * 8,
                    (char*)sB + (size_t)(w * 32 + it * 4) * 256);
        }
    }
    __syncthreads();

    // ---- MFMA: K=128 in 4 kb-steps of 32 ----
    floatx4 acc[4][4];
    #pragma unroll
    for (int i = 0; i < 4; ++i)
        #pragma unroll
        for (int j = 0; j < 4; ++j)
            acc[i][j] = (floatx4){0.f, 0.f, 0.f, 0.f};

    #pragma unroll
    for (int kb = 0; kb < 4; ++kb) {
        half8v aF[4], bF[4];
        #pragma unroll
        for (int mi = 0; mi < 4; ++mi) {
            int row = wrow + mi * 16 + c;
            int slot = (kb * 4 + g) ^ (row & 7);
            aF[mi] = *(const half8v*)((const char*)sA + row * 256 + slot * 16);
        }
        #pragma unroll
        for (int nj = 0; nj < 4; ++nj) {
            int row = wcol + nj * 16 + c;
            int slot = (kb * 4 + g) ^ (row & 7);
            bF[nj] = *(const half8v*)((const char*)sB + row * 256 + slot * 16);
        }
        #pragma unroll
        for (int mi = 0; mi < 4; ++mi)
            #pragma unroll
            for (int nj = 0; nj < 4; ++nj)
                acc[mi][nj] = __builtin_amdgcn_mfma_f32_16x16x32_f16(
                    aF[mi], bF[nj], acc[mi][nj], 0, 0, 0);
    }

    // ---- epilogue: bias prefetch (4 domains x 4 cols), add, f16 store ----
    float bv[4][4];
    #pragma unroll
    for (int nj = 0; nj < 4; ++nj) {
        int ml = mloc + wcol + nj * 16 + c;
        if (ml >= M) ml = M - 1;   // pad cols: clamped load, masked downstream
        #pragma unroll
        for (int d = 0; d < 4; ++d)
            bv[d][nj] = bias[(size_t)d * M + ml];
    }

    #pragma unroll
    for (int mi = 0; mi < 4; ++mi) {
        #pragma unroll
        for (int i = 0; i < 4; ++i) {
            int row = wrow + mi * 16 + 4 * g + i;
            int d = sdom[row];
            unsigned short* lp = logit + (size_t)(n0 + row) * MPAD + mcol + wcol + c;
            #pragma unroll
            for (int nj = 0; nj < 4; ++nj) {
                float b = (d < 2) ? (d == 0 ? bv[0][nj] : bv[1][nj])
                                  : (d == 2 ? bv[2][nj] : bv[3][nj]);
                _Float16 h = (_Float16)(acc[mi][nj][i] + b);
                lp[nj * 16] = __builtin_bit_cast(unsigned short, h);
            }
        }
    }
}

// ---------------------------------------------------------------------------
// LSE + writeout (pure streaming): one wave per row, row in registers.
// out[n][m] = v[n][m] - LSE_m(v),  v = stored f16 (logit+bias)
// ---------------------------------------------------------------------------
template<int NCH>
__global__ __launch_bounds__(256) void lsewrite_kernel(
    const unsigned short* __restrict__ logit,  // [PN][MPAD] f16 bits
    float* __restrict__ out, int M, int colOff)
{
    const int lane = threadIdx.x & 63;
    const int wv = threadIdx.x >> 6;
    const int n = blockIdx.x * 4 + wv;

    const unsigned short* lp = logit + (size_t)n * MPAD + colOff;
    float* op = out + (size_t)n * M;

    float v[NCH][8];
    float mx = -3.0e38f;

    #pragma unroll
    for (int ci = 0; ci < NCH; ++ci) {
        int base = ci * 512 + lane * 8;
        if (base < M) {
            half8v hv = *(const half8v*)&lp[base];
            #pragma unroll
            for (int j = 0; j < 8; ++j) {
                v[ci][j] = (float)hv[j];
                mx = fmaxf(mx, v[ci][j]);
            }
        } else {
            #pragma unroll
            for (int j = 0; j < 8; ++j)
                v[ci][j] = -3.0e38f;
        }
    }

    #pragma unroll
    for (int off = 1; off < 64; off <<= 1)
        mx = fmaxf(mx, __shfl_xor(mx, off));

    float s = 0.f;
    #pragma unroll
    for (int ci = 0; ci < NCH; ++ci)
        #pragma unroll
        for (int j = 0; j < 8; ++j)
            s += __expf(v[ci][j] - mx);   // masked: exp(-inf) = 0

    #pragma unroll
    for (int off = 1; off < 64; off <<= 1)
        s += __shfl_xor(s, off);

    const float lse = mx + __logf(s);

    #pragma unroll
    for (int ci = 0; ci < NCH; ++ci) {
        int base = ci * 512 + lane * 8;
        if (base < M) {
            floatx4 o0 = {v[ci][0] - lse, v[ci][1] - lse,
                          v[ci][2] - lse, v[ci][3] - lse};
            floatx4 o1 = {v[ci][4] - lse, v[ci][5] - lse,
                          v[ci][6] - lse, v[ci][7] - lse};
            __builtin_nontemporal_store(o0, (floatx4*)&op[base]);
            __builtin_nontemporal_store(o1, (floatx4*)&op[base + 4]);
        }
    }
}

// ---------------------------------------------------------------------------
extern "C" void kernel_launch(void* const* d_in, const int* in_sizes, int n_in,
                              void* d_out, int out_size, void* d_ws, size_t ws_size,
                              hipStream_t stream) {
    const float* theta  = (const float*)d_in[0];
    const float* alpha0 = (const float*)d_in[1];
    const float* alpha1 = (const float*)d_in[2];
    const float* beta   = (const float*)d_in[3];
    const float* bias0  = (const float*)d_in[4];
    const float* bias1  = (const float*)d_in[5];
    const int*   dom    = (const int*)d_in[6];

    float* out0 = (float*)d_out;
    float* out1 = out0 + (size_t)PN * PM0;

    char* ws = (char*)d_ws;
    size_t off = 0;
    auto alloc = [&](size_t bytes) { char* p = ws + off; off = (off + bytes + 255) & ~(size_t)255; return p; };
    _Float16* B2T         = (_Float16*)alloc((size_t)MPAD * KP * 2);        // 1.57 MB
    unsigned short* logit = (unsigned short*)alloc((size_t)PN * MPAD * 2);  // 201 MB

    // 1. zero B2T (pad rows + k-pad deterministically zero)
    {
        int n16 = MPAD * KP * 2 / 16;
        fill_kernel<<<(n16 + 255) / 256, 256, 0, stream>>>((uint4v*)B2T, n16);
    }

    // 2. topics (both segments, one dispatch) -> B2T f16 transposed
    topic_kernel<<<dim3(96, 5), 256, 0, stream>>>(alpha0, alpha1, beta, B2T);

    // 3. GEMM + bias -> f16 logits
    gemm_kernel<<<dim3(MPAD / 128, PN / 128), 256, 0, stream>>>(
        theta, B2T, bias0, bias1, dom, logit);

    // 4. LSE + writeout per segment
    lsewrite_kernel<8><<<PN / 4, 256, 0, stream>>>(logit, out0, PM0, 0);
    lsewrite_kernel<4><<<PN / 4, 256, 0, stream>>>(logit, out1, PM1, SEG1);
}

// Round 7
// 303.739 us; speedup vs baseline: 1.5080x; 1.2107x over previous
//
#include <hip/hip_runtime.h>
#include <hip/hip_bf16.h>

// Problem constants
#define PN 16384
#define PZ 100
#define PE 400
#define PM0 4000
#define PM1 2000
#define KP 128            // packed K: [0,100) = f16 data, [100,128) = zero
#define SEG1ROW 4096      // B2T row base of segment 1
#define MROWS 6144        // 4096 (seg0, pad from 4000) + 2048 (seg1, pad from 2000)

typedef __attribute__((ext_vector_type(8))) _Float16 half8v;
typedef __attribute__((ext_vector_type(4))) float floatx4;
typedef __attribute__((ext_vector_type(4))) unsigned int uint4v;

__device__ __forceinline__ void gload16(const void* g, void* l) {
    __builtin_amdgcn_global_load_lds(
        (const __attribute__((address_space(1))) void*)g,
        (__attribute__((address_space(3))) void*)l, 16, 0, 0);
}

// ---------------------------------------------------------------------------
// zero-fill B2T (pad rows + pad k stay deterministically zero)
// ---------------------------------------------------------------------------
__global__ __launch_bounds__(256) void fill_kernel(uint4v* __restrict__ p, int n16)
{
    int i = blockIdx.x * 256 + threadIdx.x;
    if (i < n16) p[i] = (uint4v){0u, 0u, 0u, 0u};
}

// ---------------------------------------------------------------------------
// topic (both segments, one dispatch):
// b2t[rowbase+m][z] = f16( sum_e beta[z][e] * alpha[m][e] )
// ---------------------------------------------------------------------------
__global__ __launch_bounds__(256) void topic_kernel(
    const float* __restrict__ alpha0, const float* __restrict__ alpha1,
    const float* __restrict__ beta, _Float16* __restrict__ b2t)
{
    const int seg = (blockIdx.x >= 64);
    const int tile = seg ? (blockIdx.x - 64) : blockIdx.x;
    const float* alpha = seg ? alpha1 : alpha0;
    const int M = seg ? PM1 : PM0;
    const int rowbase = seg ? SEG1ROW : 0;

    __shared__ float sA[64][201];
    const int tid = threadIdx.x;
    const int ml = tid & 63;
    const int zt = tid >> 6;
    const int m0 = tile * 64;
    const int z0 = blockIdx.y * 20 + zt * 5;

    float acc[5] = {0.f, 0.f, 0.f, 0.f, 0.f};

    for (int ec = 0; ec < 2; ++ec) {
        #pragma unroll
        for (int l = 0; l < 50; ++l) {
            int idx = tid + l * 256;
            int mr = idx / 200;
            int e  = idx - mr * 200;
            int m  = m0 + mr;
            sA[mr][e] = (m < M) ? alpha[(size_t)m * PE + ec * 200 + e] : 0.f;
        }
        __syncthreads();
        const float* bz = beta + (size_t)z0 * PE + ec * 200;
        #pragma unroll 4
        for (int e = 0; e < 200; ++e) {
            float a = sA[ml][e];
            #pragma unroll
            for (int zi = 0; zi < 5; ++zi)
                acc[zi] = fmaf(bz[zi * PE + e], a, acc[zi]);
        }
        __syncthreads();
    }
    int m = m0 + ml;
    if (m < M) {
        #pragma unroll
        for (int zi = 0; zi < 5; ++zi)
            b2t[(size_t)(rowbase + m) * KP + (z0 + zi)] = (_Float16)acc[zi];
    }
}

// ---------------------------------------------------------------------------
// Fused GEMM + online LSE + writeout, v2.
// Block: 256 threads (4 waves), 32 output rows x one full segment.
// Wave w = 16-col slice of each 64-col B tile. Per lane: 2 row-fragments.
// Double-buffered B (global_load_lds, prefetch issued AFTER the barrier so
// it has the whole MFMA+epilogue to land). One barrier per tile.
// Sweep 1: online per-row (max, sumexp) in regs. Reduce -> LSE.
// Sweep 2: recompute MFMA, write logit + bias - lse (nontemporal f32).
// LDS = 8 KB A-region (reused for sdom/partials after aF -> regs)
//     + 2 x 16 KB B buffers = exactly 40 KB -> 4 blocks/CU.
// ---------------------------------------------------------------------------
__global__ __launch_bounds__(256, 4) void fused_kernel(
    const float* __restrict__ theta,
    const _Float16* __restrict__ B2T,
    const float* __restrict__ bias0, const float* __restrict__ bias1,
    const int* __restrict__ dom,
    float* __restrict__ out0, float* __restrict__ out1)
{
    __shared__ __align__(1024) char sAreg[8192];          // A panel, then reused
    __shared__ __align__(1024) _Float16 sB[2][64 * 128];  // 2 x 16 KB

    int*   sdom = (int*)sAreg;                    // [32]   @ 0
    float* swx  = (float*)(sAreg + 128);          // [4][32]
    float* sws  = (float*)(sAreg + 128 + 512);    // [4][32]
    float* slse = (float*)(sAreg + 128 + 1024);   // [32]

    const int tid = threadIdx.x;
    const int w   = tid >> 6;
    const int ll  = tid & 63;
    const int g   = ll >> 4;     // 0..3
    const int c   = ll & 15;     // 0..15

    const int seg = blockIdx.x & 1;
    const int n0  = (blockIdx.x >> 1) * 32;
    const int M   = seg ? PM1 : PM0;
    const int NT  = seg ? 32 : 63;
    const _Float16* Bseg = B2T + (size_t)(seg ? SEG1ROW : 0) * KP;
    const float* bias = seg ? bias1 : bias0;
    float* out = seg ? out1 : out0;

    // ---- stage A panel: theta f32 -> f16, swizzled 16B slots ----
    #pragma unroll
    for (int p = 0; p < 2; ++p) {
        int idx  = tid + p * 256;       // 32 rows x 16 slots
        int row  = idx >> 4;
        int slot = idx & 15;
        const float* tr = theta + (size_t)(n0 + row) * PZ + slot * 8;
        half8v h;
        if (slot < 12) {
            float4 lo = *(const float4*)tr;
            float4 hi = *(const float4*)(tr + 4);
            h[0] = (_Float16)lo.x; h[1] = (_Float16)lo.y;
            h[2] = (_Float16)lo.z; h[3] = (_Float16)lo.w;
            h[4] = (_Float16)hi.x; h[5] = (_Float16)hi.y;
            h[6] = (_Float16)hi.z; h[7] = (_Float16)hi.w;
        } else if (slot == 12) {
            float4 lo = *(const float4*)tr;   // k = 96..99
            h[0] = (_Float16)lo.x; h[1] = (_Float16)lo.y;
            h[2] = (_Float16)lo.z; h[3] = (_Float16)lo.w;
            h[4] = (_Float16)0.f; h[5] = (_Float16)0.f;
            h[6] = (_Float16)0.f; h[7] = (_Float16)0.f;
        } else {
            h = (half8v)(_Float16)0.f;
        }
        *(half8v*)(sAreg + row * 256 + ((slot ^ (row & 7)) * 16)) = h;
    }

    // ---- B staging helper: wave w stages its 16 rows of the 64-row tile ----
    const int srow  = ll >> 4;
    const int sslot = ll & 15;
    auto stageB = [&](int buf, int t) {
        #pragma unroll
        for (int it = 0; it < 4; ++it) {
            int row  = w * 16 + it * 4 + srow;
            int slot = sslot ^ (row & 7);
            gload16(Bseg + ((size_t)t * 64 + row) * KP + slot * 8,
                    (char*)&sB[buf][0] + (w * 16 + it * 4) * 256);
        }
    };

    stageB(0, 0);          // tile 0 prefetch overlaps A staging drain
    __syncthreads();       // A panel + tile0 ready

    // ---- A fragments -> registers (kept for both sweeps) ----
    half8v aF[2][4];
    #pragma unroll
    for (int mi = 0; mi < 2; ++mi) {
        int row = mi * 16 + c;
        #pragma unroll
        for (int kb = 0; kb < 4; ++kb) {
            int slot = (kb * 4 + g) ^ (row & 7);
            aF[mi][kb] = *(const half8v*)(sAreg + row * 256 + slot * 16);
        }
    }
    __syncthreads();       // all aF reads complete -> sA region reusable
    if (tid < 32) sdom[tid] = dom[n0 + tid];
    __syncthreads();       // sdom visible

    float mx_[2][4], sm_[2][4];
    #pragma unroll
    for (int mi = 0; mi < 2; ++mi)
        #pragma unroll
        for (int i = 0; i < 4; ++i) { mx_[mi][i] = -3.0e38f; sm_[mi][i] = 0.f; }

    // =================== sweep 1: online stats ===================
    for (int t = 0; t < NT; ++t) {
        if (t) __syncthreads();          // drains prefetch of tile t
        if (t + 1 < NT) stageB((t + 1) & 1, t + 1);   // issued AFTER barrier

        half8v bF[4];
        const int brow = w * 16 + c;
        #pragma unroll
        for (int kb = 0; kb < 4; ++kb) {
            int slot = (kb * 4 + g) ^ (brow & 7);
            bF[kb] = *(const half8v*)((const char*)&sB[t & 1][0] + brow * 256 + slot * 16);
        }

        floatx4 acc[2];
        acc[0] = (floatx4){0.f, 0.f, 0.f, 0.f};
        acc[1] = (floatx4){0.f, 0.f, 0.f, 0.f};
        #pragma unroll
        for (int mi = 0; mi < 2; ++mi)
            #pragma unroll
            for (int kb = 0; kb < 4; ++kb)
                acc[mi] = __builtin_amdgcn_mfma_f32_16x16x32_f16(
                    aF[mi][kb], bF[kb], acc[mi], 0, 0, 0);

        const int m  = t * 64 + w * 16 + c;
        const bool mv = (m < M);
        const int mc = mv ? m : (M - 1);
        float bv0 = bias[0 * (size_t)M + mc];
        float bv1 = bias[1 * (size_t)M + mc];
        float bv2 = bias[2 * (size_t)M + mc];
        float bv3 = bias[3 * (size_t)M + mc];

        #pragma unroll
        for (int mi = 0; mi < 2; ++mi) {
            #pragma unroll
            for (int i = 0; i < 4; ++i) {
                int row = mi * 16 + 4 * g + i;
                int d = sdom[row];
                float bv = (d < 2) ? (d == 0 ? bv0 : bv1) : (d == 2 ? bv2 : bv3);
                float v = mv ? (acc[mi][i] + bv) : -3.0e38f;
                float nm = fmaxf(mx_[mi][i], v);
                sm_[mi][i] = sm_[mi][i] * __expf(mx_[mi][i] - nm) + __expf(v - nm);
                mx_[mi][i] = nm;
            }
        }
    }

    // ---- cross-lane reduce (16 c-lanes) ----
    #pragma unroll
    for (int mi = 0; mi < 2; ++mi) {
        #pragma unroll
        for (int i = 0; i < 4; ++i) {
            float m_ = mx_[mi][i], s_ = sm_[mi][i];
            #pragma unroll
            for (int msk = 1; msk < 16; msk <<= 1) {
                float mo = __shfl_xor(m_, msk);
                float so = __shfl_xor(s_, msk);
                float nm = fmaxf(m_, mo);
                s_ = s_ * __expf(m_ - nm) + so * __expf(mo - nm);
                m_ = nm;
            }
            if (c == 0) {
                int row = mi * 16 + 4 * g + i;
                swx[w * 32 + row] = m_;
                sws[w * 32 + row] = s_;
            }
        }
    }
    __syncthreads();       // partials visible; all sweep-1 ds_reads drained

    stageB(0, 0);          // sweep-2 tile 0 prefetch overlaps the LSE combine

    if (tid < 32) {
        float m_ = swx[tid], s_ = sws[tid];
        #pragma unroll
        for (int wv = 1; wv < 4; ++wv) {
            float mo = swx[wv * 32 + tid];
            float so = sws[wv * 32 + tid];
            float nm = fmaxf(m_, mo);
            s_ = s_ * __expf(m_ - nm) + so * __expf(mo - nm);
            m_ = nm;
        }
        slse[tid] = m_ + __logf(s_);
    }
    __syncthreads();       // slse visible + sweep-2 tile0 drained

    // =================== sweep 2: recompute + write ===================
    for (int t = 0; t < NT; ++t) {
        if (t) __syncthreads();
        if (t + 1 < NT) stageB((t + 1) & 1, t + 1);

        half8v bF[4];
        const int brow = w * 16 + c;
        #pragma unroll
        for (int kb = 0; kb < 4; ++kb) {
            int slot = (kb * 4 + g) ^ (brow & 7);
            bF[kb] = *(const half8v*)((const char*)&sB[t & 1][0] + brow * 256 + slot * 16);
        }

        floatx4 acc[2];
        acc[0] = (floatx4){0.f, 0.f, 0.f, 0.f};
        acc[1] = (floatx4){0.f, 0.f, 0.f, 0.f};
        #pragma unroll
        for (int mi = 0; mi < 2; ++mi)
            #pragma unroll
            for (int kb = 0; kb < 4; ++kb)
                acc[mi] = __builtin_amdgcn_mfma_f32_16x16x32_f16(
                    aF[mi][kb], bF[kb], acc[mi], 0, 0, 0);

        const int m  = t * 64 + w * 16 + c;
        const bool mv = (m < M);
        const int mc = mv ? m : (M - 1);
        float bv0 = bias[0 * (size_t)M + mc];
        float bv1 = bias[1 * (size_t)M + mc];
        float bv2 = bias[2 * (size_t)M + mc];
        float bv3 = bias[3 * (size_t)M + mc];

        if (mv) {
            #pragma unroll
            for (int mi = 0; mi < 2; ++mi) {
                #pragma unroll
                for (int i = 0; i < 4; ++i) {
                    int row = mi * 16 + 4 * g + i;
                    int d = sdom[row];
                    float bv = (d < 2) ? (d == 0 ? bv0 : bv1) : (d == 2 ? bv2 : bv3);
                    float o = acc[mi][i] + bv - slse[row];
                    __builtin_nontemporal_store(o, &out[(size_t)(n0 + row) * M + m]);
                }
            }
        }
    }
}

// ---------------------------------------------------------------------------
extern "C" void kernel_launch(void* const* d_in, const int* in_sizes, int n_in,
                              void* d_out, int out_size, void* d_ws, size_t ws_size,
                              hipStream_t stream) {
    const float* theta  = (const float*)d_in[0];
    const float* alpha0 = (const float*)d_in[1];
    const float* alpha1 = (const float*)d_in[2];
    const float* beta   = (const float*)d_in[3];
    const float* bias0  = (const float*)d_in[4];
    const float* bias1  = (const float*)d_in[5];
    const int*   dom    = (const int*)d_in[6];

    float* out0 = (float*)d_out;
    float* out1 = out0 + (size_t)PN * PM0;

    _Float16* B2T = (_Float16*)d_ws;   // [MROWS][KP] f16, 1.57 MB

    // 1. zero B2T (pad rows + k-pad deterministically zero)
    {
        int n16 = MROWS * KP * 2 / 16;
        fill_kernel<<<(n16 + 255) / 256, 256, 0, stream>>>((uint4v*)B2T, n16);
    }

    // 2. topics (both segments, one dispatch) -> B2T f16 transposed
    topic_kernel<<<dim3(96, 5), 256, 0, stream>>>(alpha0, alpha1, beta, B2T);

    // 3. fused GEMM + LSE + writeout: 1024 blocks = 4/CU, segs interleaved
    fused_kernel<<<(PN / 32) * 2, 256, 0, stream>>>(
        theta, B2T, bias0, bias1, dom, out0, out1);
}